// Round 1
// baseline (102.384 us; speedup 1.0000x reference)
//
#include <hip/hip_runtime.h>

#define NEG_EPS 0.01f
#define NW 376   // total staged weight floats

struct Params {
  const float* W_in;  const float* b_in;
  const float* W_out; const float* b_out;
  const float* Wl_out;const float* bl_out;
  const float* Wp[4]; const float* bp[4];
  const float* Wl[4]; const float* bl[4];
};

// NegativeLinear reparameterization (done once per block, precision-friendly expf)
__device__ __forceinline__ float neg_rep(float v) {
  return (v >= 0.0f) ? -expf(-v - NEG_EPS) : (v - expf(-NEG_EPS));
}

// -softplus(t), numerically stable for |t| up to ~1e5 magnitudes seen in ref
__device__ __forceinline__ float nsp(float t) {
  float a = fabsf(t);
  float e = __expf(-a);            // v_exp_f32 path
  float l = __logf(1.0f + e);      // log1p(e), e in (0,1] so 1+e in (1,2]
  return -(fmaxf(t, 0.0f) + l);
}

// Map flat LDS index -> weight value (with reparam applied to Wp*/W_out).
// Layout:
//   [0..20]   W_in (7x3)       [21..27] b_in
//   layer L (L=0..3) at 28+84L: [0..48] Wp^r, [49..55] bp, [56..76] Wl, [77..83] bl
//   [364..370] W_out^r, [371] b_out, [372..374] Wl_out, [375] bl_out
__device__ float fetch_w(int i, const Params& p) {
  if (i < 21) return p.W_in[i];
  if (i < 28) return p.b_in[i - 21];
  i -= 28;
  if (i < 336) {
    int L = i / 84, r = i % 84;
    if (r < 49) return neg_rep(p.Wp[L][r]);
    if (r < 56) return p.bp[L][r - 49];
    if (r < 77) return p.Wl[L][r - 56];
    return p.bl[L][r - 77];
  }
  i -= 336;
  if (i < 7)  return neg_rep(p.W_out[i]);
  if (i == 7) return p.b_out[0];
  if (i < 11) return p.Wl_out[i - 8];
  return p.bl_out[0];
}

__global__ __launch_bounds__(256) void entropy_fwd(
    const float4* __restrict__ x4, float4* __restrict__ out4,
    Params p, int nthreads) {
  __shared__ float w[NW];
  for (int i = threadIdx.x; i < NW; i += 256) w[i] = fetch_w(i, p);
  __syncthreads();

  int idx = blockIdx.x * 256 + threadIdx.x;
  if (idx >= nthreads) return;

  // 4 rows per thread: 3 aligned float4 loads
  float4 a = x4[idx * 3 + 0];
  float4 b = x4[idx * 3 + 1];
  float4 c = x4[idx * 3 + 2];
  float X[4][3] = {{a.x, a.y, a.z}, {a.w, b.x, b.y},
                   {b.z, b.w, c.x}, {c.y, c.z, c.w}};

  float h[4][7];

  // input layer: h = -sp(x0 @ W_in.T + b_in)
  #pragma unroll
  for (int r = 0; r < 4; ++r) {
    #pragma unroll
    for (int j = 0; j < 7; ++j) {
      float acc = w[21 + j];
      #pragma unroll
      for (int d = 0; d < 3; ++d) acc = fmaf(w[j * 3 + d], X[r][d], acc);
      h[r][j] = nsp(acc);
    }
  }

  // 4 residual-style layers
  #pragma unroll
  for (int L = 0; L < 4; ++L) {
    const int off = 28 + L * 84;
    float hn[4][7];
    #pragma unroll
    for (int r = 0; r < 4; ++r) {
      #pragma unroll
      for (int j = 0; j < 7; ++j) {
        float acc = w[off + 49 + j] + w[off + 77 + j];  // bp + bl
        #pragma unroll
        for (int k = 0; k < 7; ++k) acc = fmaf(w[off + j * 7 + k], h[r][k], acc);
        #pragma unroll
        for (int d = 0; d < 3; ++d) acc = fmaf(w[off + 56 + j * 3 + d], X[r][d], acc);
        hn[r][j] = nsp(acc);
      }
    }
    #pragma unroll
    for (int r = 0; r < 4; ++r) {
      #pragma unroll
      for (int j = 0; j < 7; ++j) h[r][j] = hn[r][j];
    }
  }

  // output layer
  float4 o;
  float* op = &o.x;
  #pragma unroll
  for (int r = 0; r < 4; ++r) {
    float acc = w[371] + w[375];  // b_out + bl_out
    #pragma unroll
    for (int k = 0; k < 7; ++k) acc = fmaf(w[364 + k], h[r][k], acc);
    #pragma unroll
    for (int d = 0; d < 3; ++d) acc = fmaf(w[372 + d], X[r][d], acc);
    op[r] = nsp(acc);
  }
  out4[idx] = o;
}

extern "C" void kernel_launch(void* const* d_in, const int* in_sizes, int n_in,
                              void* d_out, int out_size, void* d_ws, size_t ws_size,
                              hipStream_t stream) {
  (void)n_in; (void)d_ws; (void)ws_size;
  Params p;
  p.W_in   = (const float*)d_in[1];
  p.b_in   = (const float*)d_in[2];
  p.W_out  = (const float*)d_in[3];
  p.b_out  = (const float*)d_in[4];
  p.Wl_out = (const float*)d_in[5];
  p.bl_out = (const float*)d_in[6];
  for (int i = 0; i < 4; ++i) {
    p.Wp[i] = (const float*)d_in[7 + 4 * i];
    p.bp[i] = (const float*)d_in[8 + 4 * i];
    p.Wl[i] = (const float*)d_in[9 + 4 * i];
    p.bl[i] = (const float*)d_in[10 + 4 * i];
  }

  int n_rows   = in_sizes[0] / 3;          // 4194304
  int nthreads = (n_rows + 3) / 4;         // 4 rows per thread
  int blocks   = (nthreads + 255) / 256;   // 4096 blocks

  entropy_fwd<<<blocks, 256, 0, stream>>>(
      (const float4*)d_in[0], (float4*)d_out, p, nthreads);
}

// Round 2
// 100.378 us; speedup vs baseline: 1.0200x; 1.0200x over previous
//
#include <hip/hip_runtime.h>

#define NEG_EPS 0.01f
#define NW4 94            // float4 count of staged weights
#define NW  (NW4 * 4)     // 376 floats

struct Params {
  const float* W_in;  const float* b_in;
  const float* W_out; const float* b_out;
  const float* Wl_out;const float* bl_out;
  const float* Wp[4]; const float* bp[4];
  const float* Wl[4]; const float* bl[4];
};

// m = -Wr where Wr is the NegativeLinear reparameterized weight (m > 0)
__device__ __forceinline__ float neg_rep_m(float v) {
  return (v >= 0.0f) ? expf(-v - NEG_EPS) : (expf(-NEG_EPS) - v);
}

// softplus, stable: sp(t) = max(t,0) + log1p(exp(-|t|))
__device__ __forceinline__ float sp_fast(float t) {
  float e = __expf(-fabsf(t));
  return fmaxf(t, 0.0f) + __logf(1.0f + e);
}

// Staged float4 layout:
//  j=0..6:            w4[j]        = {W_in[j][0..2], b_in[j]}
//  hidden L, j=0..6:  b=7+21L+3j:  w4[b]   = {m[j][0..3]}          (m = -Wp^r)
//                                  w4[b+1] = {m[j][4..6], Wl[j][0]}
//                                  w4[b+2] = {Wl[j][1], Wl[j][2], bp[j]+bl[j], 0}
//  output:            w4[91..93]  = same 12-float pattern for W_out/Wl_out/b
__device__ float fetch_w(int i, const Params& p) {
  if (i < 28) {
    int j = i >> 2, c = i & 3;
    return (c < 3) ? p.W_in[j * 3 + c] : p.b_in[j];
  }
  if (i < 364) {
    int k = i - 28, L = k / 84, r = k % 84, j = r / 12, c = r % 12;
    if (c < 7)  return neg_rep_m(p.Wp[L][j * 7 + c]);
    if (c < 10) return p.Wl[L][j * 3 + (c - 7)];
    if (c == 10) return p.bp[L][j] + p.bl[L][j];
    return 0.0f;
  }
  int r = i - 364;
  if (r < 7)  return neg_rep_m(p.W_out[r]);
  if (r < 10) return p.Wl_out[r - 7];
  if (r == 10) return p.b_out[0] + p.bl_out[0];
  return 0.0f;
}

// one hidden layer for 4 rows: hout = sp( m·hin + Wl·x0 + bias )
__device__ __forceinline__ void layer_fwd(const float4* __restrict__ wb,
                                          const float (&hi)[4][7],
                                          float (&ho)[4][7],
                                          const float (&X)[4][3]) {
  #pragma unroll
  for (int j = 0; j < 7; ++j) {
    float4 a = wb[j * 3 + 0];
    float4 b = wb[j * 3 + 1];
    float4 c = wb[j * 3 + 2];
    #pragma unroll
    for (int r = 0; r < 4; ++r) {
      float acc = c.z;
      acc = fmaf(a.x, hi[r][0], acc);
      acc = fmaf(a.y, hi[r][1], acc);
      acc = fmaf(a.z, hi[r][2], acc);
      acc = fmaf(a.w, hi[r][3], acc);
      acc = fmaf(b.x, hi[r][4], acc);
      acc = fmaf(b.y, hi[r][5], acc);
      acc = fmaf(b.z, hi[r][6], acc);
      acc = fmaf(b.w, X[r][0], acc);
      acc = fmaf(c.x, X[r][1], acc);
      acc = fmaf(c.y, X[r][2], acc);
      ho[r][j] = sp_fast(acc);
    }
  }
}

__global__ __launch_bounds__(256) void entropy_fwd(
    const float4* __restrict__ x4, float4* __restrict__ out4,
    Params p, int nthreads) {
  __shared__ float4 w4[NW4];
  {
    float* w = (float*)w4;
    for (int i = threadIdx.x; i < NW; i += 256) w[i] = fetch_w(i, p);
  }
  __syncthreads();

  int idx = blockIdx.x * 256 + threadIdx.x;
  if (idx >= nthreads) return;

  float4 a = x4[idx * 3 + 0];
  float4 b = x4[idx * 3 + 1];
  float4 c = x4[idx * 3 + 2];
  float X[4][3] = {{a.x, a.y, a.z}, {a.w, b.x, b.y},
                   {b.z, b.w, c.x}, {c.y, c.z, c.w}};

  float h0[4][7], h1[4][7];

  // input layer: s = sp(x0 @ W_in.T + b_in)
  #pragma unroll
  for (int j = 0; j < 7; ++j) {
    float4 wi = w4[j];
    #pragma unroll
    for (int r = 0; r < 4; ++r) {
      float acc = wi.w;
      acc = fmaf(wi.x, X[r][0], acc);
      acc = fmaf(wi.y, X[r][1], acc);
      acc = fmaf(wi.z, X[r][2], acc);
      h0[r][j] = sp_fast(acc);
    }
  }

  // 4 hidden layers, ping-pong
  layer_fwd(&w4[7 + 0 * 21], h0, h1, X);
  layer_fwd(&w4[7 + 1 * 21], h1, h0, X);
  layer_fwd(&w4[7 + 2 * 21], h0, h1, X);
  layer_fwd(&w4[7 + 3 * 21], h1, h0, X);

  // output layer: S = -sp( m_out·s + Wl_out·x0 + b )
  float4 o;
  float* op = &o.x;
  {
    float4 wa = w4[91], wb = w4[92], wc = w4[93];
    #pragma unroll
    for (int r = 0; r < 4; ++r) {
      float acc = wc.z;
      acc = fmaf(wa.x, h0[r][0], acc);
      acc = fmaf(wa.y, h0[r][1], acc);
      acc = fmaf(wa.z, h0[r][2], acc);
      acc = fmaf(wa.w, h0[r][3], acc);
      acc = fmaf(wb.x, h0[r][4], acc);
      acc = fmaf(wb.y, h0[r][5], acc);
      acc = fmaf(wb.z, h0[r][6], acc);
      acc = fmaf(wb.w, X[r][0], acc);
      acc = fmaf(wc.x, X[r][1], acc);
      acc = fmaf(wc.y, X[r][2], acc);
      op[r] = -sp_fast(acc);
    }
  }
  out4[idx] = o;
}

extern "C" void kernel_launch(void* const* d_in, const int* in_sizes, int n_in,
                              void* d_out, int out_size, void* d_ws, size_t ws_size,
                              hipStream_t stream) {
  (void)n_in; (void)d_ws; (void)ws_size;
  Params p;
  p.W_in   = (const float*)d_in[1];
  p.b_in   = (const float*)d_in[2];
  p.W_out  = (const float*)d_in[3];
  p.b_out  = (const float*)d_in[4];
  p.Wl_out = (const float*)d_in[5];
  p.bl_out = (const float*)d_in[6];
  for (int i = 0; i < 4; ++i) {
    p.Wp[i] = (const float*)d_in[7 + 4 * i];
    p.bp[i] = (const float*)d_in[8 + 4 * i];
    p.Wl[i] = (const float*)d_in[9 + 4 * i];
    p.bl[i] = (const float*)d_in[10 + 4 * i];
  }

  int n_rows   = in_sizes[0] / 3;
  int nthreads = (n_rows + 3) / 4;
  int blocks   = (nthreads + 255) / 256;

  entropy_fwd<<<blocks, 256, 0, stream>>>(
      (const float4*)d_in[0], (float4*)d_out, p, nthreads);
}

// Round 3
// 61.725 us; speedup vs baseline: 1.6587x; 1.6262x over previous
//
#include <hip/hip_runtime.h>
#include <math.h>

#define NEG_EPS 0.01f
#define LOG2E 1.4426950408889634f
#define LN2   0.6931471805599453f
#define NW 404   // staged floats (101 float4)

typedef float f32x2 __attribute__((ext_vector_type(2)));

#if __has_builtin(__builtin_amdgcn_exp2f)
#define EXP2F(x) __builtin_amdgcn_exp2f(x)
#else
#define EXP2F(x) exp2f(x)
#endif
#if __has_builtin(__builtin_amdgcn_logf)
#define LOG2F(x) __builtin_amdgcn_logf(x)
#else
#define LOG2F(x) __log2f(x)
#endif

struct Params {
  const float* W_in;  const float* b_in;
  const float* W_out; const float* b_out;
  const float* Wl_out;const float* bl_out;
  const float* Wp[4]; const float* bp[4];
  const float* Wl[4]; const float* bl[4];
};

// m = -Wr (positive); Wr is the NegativeLinear reparameterized weight
__device__ __forceinline__ float neg_rep_m(float v) {
  return (v >= 0.0f) ? expf(-v - NEG_EPS) : (expf(-NEG_EPS) - v);
}

// ---- packed fp32 helpers (VOP3P). op_sel broadcast selects one 32-bit half
// of the weight pair for BOTH result lanes.
__device__ __forceinline__ f32x2 pk_fma_lo(f32x2 w, f32x2 v, f32x2 c) {
  f32x2 d;
  asm("v_pk_fma_f32 %0, %1, %2, %3 op_sel:[0,0,0] op_sel_hi:[0,1,1]"
      : "=v"(d) : "v"(w), "v"(v), "v"(c));
  return d;
}
__device__ __forceinline__ f32x2 pk_fma_hi(f32x2 w, f32x2 v, f32x2 c) {
  f32x2 d;
  asm("v_pk_fma_f32 %0, %1, %2, %3 op_sel:[1,0,0] op_sel_hi:[1,1,1]"
      : "=v"(d) : "v"(w), "v"(v), "v"(c));
  return d;
}

// H(t') = max(t',0) + log2(1 + 2^(-|t'|))  ==  log2e * softplus(t'/log2e)
__device__ __forceinline__ f32x2 H2f(f32x2 t) {
  f32x2 r;
  float ex = EXP2F(-fabsf(t.x));          // v_exp_f32 with -|.| modifiers
  float ey = EXP2F(-fabsf(t.y));
  float lx = LOG2F(1.0f + ex);            // v_add(1.0 inline) + v_log_f32
  float ly = LOG2F(1.0f + ey);
  r.x = fmaxf(t.x, 0.0f) + lx;
  r.y = fmaxf(t.y, 0.0f) + ly;
  return r;
}

// Staged layout (floats):
//  input neuron j (8 floats @ 8j):   {c*Wi[j][0..2], 0, c*b_in[j], c*b_in[j], 0, 0}
//  hidden L, neuron j (12 @ 56+84L+12j): {m[j][0..6], c*Wl[j][0..2], c*bb, c*bb}
//  output (12 @ 392): same 12-float record        (c = log2e, bb = bp+bl)
__device__ float fetch_w(int i, const Params& p) {
  if (i < 56) {
    int j = i >> 3, c_ = i & 7;
    if (c_ < 3) return LOG2E * p.W_in[j * 3 + c_];
    if (c_ == 4 || c_ == 5) return LOG2E * p.b_in[j];
    return 0.0f;
  }
  i -= 56;
  if (i < 336) {
    int L = i / 84, r = i % 84, j = r / 12, c_ = r % 12;
    if (c_ < 7)  return neg_rep_m(p.Wp[L][j * 7 + c_]);
    if (c_ < 10) return LOG2E * p.Wl[L][j * 3 + (c_ - 7)];
    return LOG2E * (p.bp[L][j] + p.bl[L][j]);
  }
  i -= 336;
  if (i < 7)  return neg_rep_m(p.W_out[i]);
  if (i < 10) return LOG2E * p.Wl_out[i - 7];
  return LOG2E * (p.b_out[0] + p.bl_out[0]);
}

// 10-dim dot for one row-pair: wp pairs {(m0,m1)(m2,m3)(m4,m5)(m6,wl0)(wl1,wl2)(b,b)}
__device__ __forceinline__ f32x2 dot10(f32x2 w0, f32x2 w1, f32x2 w2_,
                                       f32x2 w3, f32x2 w4_, f32x2 w5,
                                       const f32x2 (&H)[7], const f32x2 (&X)[3]) {
  f32x2 acc = w5;
  acc = pk_fma_lo(w0, H[0], acc);
  acc = pk_fma_hi(w0, H[1], acc);
  acc = pk_fma_lo(w1, H[2], acc);
  acc = pk_fma_hi(w1, H[3], acc);
  acc = pk_fma_lo(w2_, H[4], acc);
  acc = pk_fma_hi(w2_, H[5], acc);
  acc = pk_fma_lo(w3, H[6], acc);
  acc = pk_fma_hi(w3, X[0], acc);
  acc = pk_fma_lo(w4_, X[1], acc);
  acc = pk_fma_hi(w4_, X[2], acc);
  return acc;
}

__global__ __launch_bounds__(256) void entropy_fwd(
    const float4* __restrict__ x4, float4* __restrict__ out4,
    Params p, int nthreads) {
  __shared__ float wsm[NW];
  for (int i = threadIdx.x; i < NW; i += 256) wsm[i] = fetch_w(i, p);
  __syncthreads();
  const f32x2* w2 = (const f32x2*)wsm;

  int idx = blockIdx.x * 256 + threadIdx.x;
  if (idx >= nthreads) return;

  float4 a = x4[idx * 3 + 0];
  float4 b = x4[idx * 3 + 1];
  float4 c = x4[idx * 3 + 2];
  // rows 0,1 packed in *a arrays; rows 2,3 in *b arrays
  f32x2 Xa[3] = {{a.x, a.w}, {a.y, b.x}, {a.z, b.y}};
  f32x2 Xb[3] = {{b.z, c.y}, {b.w, c.z}, {c.x, c.w}};

  f32x2 Ha[7], Hb[7];

  // input layer
  #pragma unroll
  for (int j = 0; j < 7; ++j) {
    const f32x2* rec = w2 + 4 * j;
    f32x2 r0 = rec[0], r1 = rec[1], r2v = rec[2];
    f32x2 ta = r2v, tb = r2v;
    ta = pk_fma_lo(r0, Xa[0], ta);  tb = pk_fma_lo(r0, Xb[0], tb);
    ta = pk_fma_hi(r0, Xa[1], ta);  tb = pk_fma_hi(r0, Xb[1], tb);
    ta = pk_fma_lo(r1, Xa[2], ta);  tb = pk_fma_lo(r1, Xb[2], tb);
    Ha[j] = H2f(ta);
    Hb[j] = H2f(tb);
  }

  // 4 hidden layers
  #pragma unroll
  for (int L = 0; L < 4; ++L) {
    const f32x2* base = w2 + 28 + 42 * L;
    f32x2 Na[7], Nb[7];
    #pragma unroll
    for (int j = 0; j < 7; ++j) {
      const f32x2* wp = base + 6 * j;
      f32x2 w0 = wp[0], w1 = wp[1], w2_ = wp[2], w3 = wp[3], w4_ = wp[4], w5 = wp[5];
      Na[j] = H2f(dot10(w0, w1, w2_, w3, w4_, w5, Ha, Xa));
      Nb[j] = H2f(dot10(w0, w1, w2_, w3, w4_, w5, Hb, Xb));
    }
    #pragma unroll
    for (int j = 0; j < 7; ++j) { Ha[j] = Na[j]; Hb[j] = Nb[j]; }
  }

  // output layer: S = -ln2 * H(t'_out)
  {
    const f32x2* wp = w2 + 196;
    f32x2 w0 = wp[0], w1 = wp[1], w2_ = wp[2], w3 = wp[3], w4_ = wp[4], w5 = wp[5];
    f32x2 HA = H2f(dot10(w0, w1, w2_, w3, w4_, w5, Ha, Xa));
    f32x2 HB = H2f(dot10(w0, w1, w2_, w3, w4_, w5, Hb, Xb));
    float4 o;
    o.x = -LN2 * HA.x;
    o.y = -LN2 * HA.y;
    o.z = -LN2 * HB.x;
    o.w = -LN2 * HB.y;
    out4[idx] = o;
  }
}

extern "C" void kernel_launch(void* const* d_in, const int* in_sizes, int n_in,
                              void* d_out, int out_size, void* d_ws, size_t ws_size,
                              hipStream_t stream) {
  (void)n_in; (void)d_ws; (void)ws_size;
  Params p;
  p.W_in   = (const float*)d_in[1];
  p.b_in   = (const float*)d_in[2];
  p.W_out  = (const float*)d_in[3];
  p.b_out  = (const float*)d_in[4];
  p.Wl_out = (const float*)d_in[5];
  p.bl_out = (const float*)d_in[6];
  for (int i = 0; i < 4; ++i) {
    p.Wp[i] = (const float*)d_in[7 + 4 * i];
    p.bp[i] = (const float*)d_in[8 + 4 * i];
    p.Wl[i] = (const float*)d_in[9 + 4 * i];
    p.bl[i] = (const float*)d_in[10 + 4 * i];
  }

  int n_rows   = in_sizes[0] / 3;
  int nthreads = (n_rows + 3) / 4;
  int blocks   = (nthreads + 255) / 256;

  entropy_fwd<<<blocks, 256, 0, stream>>>(
      (const float4*)d_in[0], (float4*)d_out, p, nthreads);
}